// Round 5
// baseline (121.772 us; speedup 1.0000x reference)
//
#include <hip/hip_runtime.h>
#include <hip/hip_bf16.h>

#define D_IN   246
#define NW     10
#define NG     4
#define FANIN  256
#define BATCH  256
#define TSTEPS 64
#define ZSTR   42          // zl row stride (pad 40 -> 42: 4-way max on scatter writes)
#define WP_ELEMS (NG * D_IN * 16)   // 15744 floats, transposed/padded W

// ---------------- Kernel 0: transpose W -> Wp[g][i][16] (o padded to 16) ---------
__global__ __launch_bounds__(256) void k_wt(const float* __restrict__ W,
                                            float* __restrict__ Wp) {
    int e = blockIdx.x * 256 + threadIdx.x;
    if (e >= WP_ELEMS) return;
    int o = e & 15;
    int i = (e >> 4) % D_IN;
    int g = e / (16 * D_IN);
    float v = (o < NW) ? W[(g * NW + o) * FANIN + i] : 0.f;
    Wp[e] = v;
}

// ---------------- Fused kernel: one block per batch element -----------------
// Phase A: stage x[.,b,.] (64 rows x 246) into LDS, coalesced.
// Phase B: GEMM. wave = gate g (wave-uniform -> Wp via scalar loads), lane = t.
// Phase C: wave 0 runs the 64-step LSTM scan from LDS; waves 1-3 exit.
template <int CTRL>
__device__ __forceinline__ float dpp_shr_mul(float p) {
    int up = __builtin_amdgcn_update_dpp(__float_as_int(1.0f), __float_as_int(p),
                                         CTRL, 0xF, 0xF, false);
    return p * __int_as_float(up);
}

__global__ __launch_bounds__(256) void k_fused(
    const float* __restrict__ x,      // (64,256,246)
    const float* __restrict__ Wp,     // (4,246,16)
    const float* __restrict__ bias,   // (4,10)
    const float* __restrict__ theta,  // (4,10)
    const float* __restrict__ W,      // (4,10,256) for recurrent cols 246..255
    float* __restrict__ out,          // (64,256,10)
    float* __restrict__ hxout,        // (256,10)
    float* __restrict__ cxout)        // (256,10)
{
    const int b    = blockIdx.x;
    const int tid  = threadIdx.x;
    const int lane = tid & 63;
    const int wv   = __builtin_amdgcn_readfirstlane(tid >> 6);

    __shared__ float xl[64 * D_IN];       // 62.98 KB
    __shared__ float zl[TSTEPS * ZSTR];   // 10.75 KB

    // ---- Phase A: stage x rows (each wave: 16 rows; lane covers 123 float2) ----
    for (int row = wv; row < 64; row += 4) {
        const float* src = x + ((size_t)row * BATCH + b) * D_IN;
        float* dst = xl + row * D_IN;
        for (int j = lane; j < 123; j += 64) {
            float2 v = *reinterpret_cast<const float2*>(src + 2 * j);
            *reinterpret_cast<float2*>(dst + 2 * j) = v;
        }
    }
    __syncthreads();

    // ---- Phase B: zx GEMM (g = wv, t = lane) ----
    {
        const int g = wv;
        float acc[NW];
#pragma unroll
        for (int o = 0; o < NW; ++o)
            acc[o] = bias[g * NW + o] + theta[g * NW + o];   // uniform -> s_load

        const float* wg = Wp + g * D_IN * 16;                // uniform base -> s_load stream
        const float* xr = xl + lane * D_IN;

#pragma unroll 4
        for (int ii = 0; ii < 123; ++ii) {
            float2 xv = *reinterpret_cast<const float2*>(xr + 2 * ii);
#pragma unroll
            for (int o = 0; o < NW; ++o) {
                acc[o] = fmaf(xv.x, wg[(2 * ii) * 16 + o], acc[o]);
                acc[o] = fmaf(xv.y, wg[(2 * ii + 1) * 16 + o], acc[o]);
            }
        }

        float* zo = zl + lane * ZSTR + g * NW;
#pragma unroll
        for (int q = 0; q < 5; ++q)
            *reinterpret_cast<float2*>(zo + 2 * q) = make_float2(acc[2 * q], acc[2 * q + 1]);
    }
    __syncthreads();

    if (wv != 0) return;   // waves 1-3 done (no further barriers)

    // ---- Phase C: sequential scan on wave 0 ----
    const int r   = lane >> 4;       // gate row
    const int o   = lane & 15;
    const bool act = (o < NW);
    const int oc  = act ? o : 0;
    const int cidx = r * NW + oc;

    float wh[NW];
#pragma unroll
    for (int j = 0; j < NW; ++j)
        wh[j] = W[(r * NW + oc) * FANIN + D_IN + j];

    // per-lane activation constants: sigmoid for f,i,o; tanh(x)=2*sigmoid(2x)-1 for g
    const float am = (r == 2) ? 2.f : 1.f;
    const float vm = (r == 2) ? 2.f : 1.f;
    const float vc = (r == 2) ? -1.f : 0.f;
    const int idx1 = (lane ^ 16) << 2;
    const int idx2 = (lane ^ 32) << 2;
    const int idx3 = (lane ^ 48) << 2;
    const bool q1 = (r & 1) != 0;
    const bool q2 = (r & 2) != 0;

    float hx_s[NW];
#pragma unroll
    for (int j = 0; j < NW; ++j) hx_s[j] = 0.f;

    float cx = 0.f, hv = 0.f;
    float zc = zl[cidx];

    for (int t = 0; t < TSTEPS; ++t) {
        // prefetch next step's pre-activation (off-chain)
        float zn = zl[((t + 1) & 63) * ZSTR + cidx];

        // z = zc + hx.wh  (two parallel fma chains)
        float s0 = zc, s1 = 0.f;
#pragma unroll
        for (int j = 0; j < 5; ++j) {
            s0 = fmaf(hx_s[2 * j],     wh[2 * j],     s0);
            s1 = fmaf(hx_s[2 * j + 1], wh[2 * j + 1], s1);
        }
        float z = s0 + s1;

        float cv = __cosf(z);

        // inclusive prefix product over the 16-lane group (DPP, VALU-only)
        float p = cv;
        p = dpp_shr_mul<0x111>(p);
        p = dpp_shr_mul<0x112>(p);
        p = dpp_shr_mul<0x114>(p);
        p = dpp_shr_mul<0x118>(p);

        // activation with per-lane fused constants
        float e  = __expf(-(p * am));
        float sg = __fdividef(1.f, 1.f + e);
        float val = fmaf(sg, vm, vc);

        // gather the other 3 rows' values (parallel bpermutes)
        int vi = __float_as_int(val);
        float a1 = __int_as_float(__builtin_amdgcn_ds_bpermute(idx1, vi)); // row^1
        float a2 = __int_as_float(__builtin_amdgcn_ds_bpermute(idx2, vi)); // row^2
        float a3 = __int_as_float(__builtin_amdgcn_ds_bpermute(idx3, vi)); // row^3

        float fv = q2 ? (q1 ? a3 : a2) : (q1 ? a1 : val);
        float iv = q2 ? (q1 ? a2 : a3) : (q1 ? val : a1);
        float gv = q2 ? (q1 ? a1 : val) : (q1 ? a3 : a2);
        float ov = q2 ? (q1 ? val : a1) : (q1 ? a2 : a3);

        cx = fmaf(fv, cx, iv * gv);
        float e2 = __expf(cx + cx);
        float th = 1.f - __fdividef(2.f, 1.f + e2);
        hv = ov * th;

        if (r == 0 && act) out[((size_t)t * BATCH + b) * NW + o] = hv;

        // broadcast hx via readlane -> SGPRs
#pragma unroll
        for (int j = 0; j < NW; ++j)
            hx_s[j] = __int_as_float(__builtin_amdgcn_readlane(__float_as_int(hv), j));

        zc = zn;
    }

    if (r == 0 && act) {
        hxout[b * NW + o] = hv;
        cxout[b * NW + o] = cx;
    }
}

extern "C" void kernel_launch(void* const* d_in, const int* in_sizes, int n_in,
                              void* d_out, int out_size, void* d_ws, size_t ws_size,
                              hipStream_t stream) {
    const float* x     = (const float*)d_in[0];  // (64,256,246)
    const float* W     = (const float*)d_in[1];  // (4,10,256)
    const float* bias  = (const float*)d_in[2];  // (4,10)
    const float* theta = (const float*)d_in[3];  // (4,10)

    float* out   = (float*)d_out;                        // (64,256,10)
    float* hxout = out + (size_t)TSTEPS * BATCH * NW;    // (256,10)
    float* cxout = hxout + (size_t)BATCH * NW;           // (256,10)

    float* Wp = (float*)d_ws;                  // 15744 floats

    k_wt<<<(WP_ELEMS + 255) / 256, 256, 0, stream>>>(W, Wp);
    k_fused<<<BATCH, 256, 0, stream>>>(x, Wp, bias, theta, W, out, hxout, cxout);
}

// Round 6
// 116.619 us; speedup vs baseline: 1.0442x; 1.0442x over previous
//
#include <hip/hip_runtime.h>
#include <hip/hip_bf16.h>

#define D_IN   246
#define NW     10
#define NG     4
#define NOUT   40
#define FANIN  256
#define BATCH  256
#define TSTEPS 64
#define WP_ELEMS (NG * D_IN * 16)   // 15744 floats, transposed/padded W

// ---------------- Kernel 0: transpose W -> Wp[g][i][16] (o padded to 16) ---------
__global__ __launch_bounds__(256) void k_wt(const float* __restrict__ W,
                                            float* __restrict__ Wp) {
    int e = blockIdx.x * 256 + threadIdx.x;
    if (e >= WP_ELEMS) return;
    int o = e & 15;
    int i = (e >> 4) % D_IN;
    int g = e / (16 * D_IN);
    float v = (o < NW) ? W[(g * NW + o) * FANIN + i] : 0.f;
    Wp[e] = v;
}

template <int CTRL>
__device__ __forceinline__ float dpp_shr_mul(float p) {
    int up = __builtin_amdgcn_update_dpp(__float_as_int(1.0f), __float_as_int(p),
                                         CTRL, 0xF, 0xF, false);
    return p * __int_as_float(up);
}

// ---------------- Fused kernel: one block (512 thr, 8 waves) per batch element --
// A: stage x[.,b,.] into LDS.  B: GEMM, wave=(g,kh) K-split, zl[t][o][g] to LDS.
// C: wave 0 scan — all 4 gates in-lane (lane=o), VALU-only chain.
__global__ __launch_bounds__(512) void k_fused(
    const float* __restrict__ x,      // (64,256,246)
    const float* __restrict__ Wp,     // (4,246,16)
    const float* __restrict__ bias,   // (4,10)
    const float* __restrict__ theta,  // (4,10)
    const float* __restrict__ W,      // (4,10,256): recurrent cols 246..255
    float* __restrict__ out,          // (64,256,10)
    float* __restrict__ hxout,        // (256,10)
    float* __restrict__ cxout)        // (256,10)
{
    const int b    = blockIdx.x;
    const int tid  = threadIdx.x;
    const int lane = tid & 63;
    const int wv   = __builtin_amdgcn_readfirstlane(tid >> 6);
    const int g    = wv & 3;
    const int kh   = wv >> 2;

    __shared__ float xl[64 * D_IN];       // 62.98 KB
    __shared__ float pr[NG][64][NW];      // 10.24 KB  (kh=1 partials)
    __shared__ float zl[TSTEPS * NOUT];   // 10.24 KB  [t][o][g]

    // ---- wave-0 preload of recurrent weights (latency hides under staging) ----
    const int o16 = lane & 15;
    const int oc  = (o16 < NW) ? o16 : 0;
    float wh[NG][NW];
    if (wv == 0) {
#pragma unroll
        for (int gg = 0; gg < NG; ++gg)
#pragma unroll
            for (int j = 0; j < NW; ++j)
                wh[gg][j] = W[(gg * NW + oc) * FANIN + D_IN + j];
    }

    // ---- Phase A: stage x rows (8 rows/wave, coalesced float2) ----
    for (int row = wv; row < 64; row += 8) {
        const float* src = x + ((size_t)row * BATCH + b) * D_IN;
        float* dst = xl + row * D_IN;
        for (int j = lane; j < 123; j += 64) {
            float2 v = *reinterpret_cast<const float2*>(src + 2 * j);
            *reinterpret_cast<float2*>(dst + 2 * j) = v;
        }
    }
    __syncthreads();

    // ---- Phase B: zx GEMM, K-split halves (124 / 122) ----
    {
        const int khbase = kh ? 124 : 0;
        const int npairs = kh ? 61 : 62;

        float acc[NW];
#pragma unroll
        for (int o = 0; o < NW; ++o) acc[o] = 0.f;

        const float* wg = Wp + (g * D_IN + khbase) * 16;   // wave-uniform -> s_load
        const float* xr = xl + lane * D_IN + khbase;

#pragma unroll 4
        for (int ii = 0; ii < npairs; ++ii) {
            float2 xv = *reinterpret_cast<const float2*>(xr + 2 * ii);
#pragma unroll
            for (int o = 0; o < NW; ++o) {
                acc[o] = fmaf(xv.x, wg[(2 * ii)     * 16 + o], acc[o]);
                acc[o] = fmaf(xv.y, wg[(2 * ii + 1) * 16 + o], acc[o]);
            }
        }

        if (kh == 1) {
#pragma unroll
            for (int o = 0; o < NW; ++o) pr[g][lane][o] = acc[o];
        }
        __syncthreads();

        if (kh == 0) {
#pragma unroll
            for (int o = 0; o < NW; ++o) {
                float v = acc[o] + pr[g][lane][o] + bias[g * NW + o] + theta[g * NW + o];
                zl[lane * NOUT + o * NG + g] = v;   // [t][o][g]
            }
        }
    }
    __syncthreads();
    if (wv != 0) return;

    // ---- Phase C: 64-step scan, all gates in-lane, VALU-only chain ----
    float hx_s[NW];
#pragma unroll
    for (int j = 0; j < NW; ++j) hx_s[j] = 0.f;
    float cx = 0.f, hv = 0.f;

    const float* zrow = zl + oc * NG;
    float4 zn = *reinterpret_cast<const float4*>(zrow);          // t = 0
    float* outp = out + (size_t)b * NW + oc;

    for (int t = 0; t < TSTEPS; ++t) {
        float4 zc4 = zn;
        zn = *reinterpret_cast<const float4*>(zrow + ((t + 1) & 63) * NOUT); // off-chain prefetch

        float z0 = zc4.x, z1 = zc4.y, z2 = zc4.z, z3 = zc4.w;
#pragma unroll
        for (int j = 0; j < NW; ++j) {
            z0 = fmaf(hx_s[j], wh[0][j], z0);
            z1 = fmaf(hx_s[j], wh[1][j], z1);
            z2 = fmaf(hx_s[j], wh[2][j], z2);
            z3 = fmaf(hx_s[j], wh[3][j], z3);
        }

        float p0 = __cosf(z0), p1 = __cosf(z1), p2 = __cosf(z2), p3 = __cosf(z3);

        // inclusive prefix product over lanes (16-row DPP scan, 4 gates interleaved)
        p0 = dpp_shr_mul<0x111>(p0); p1 = dpp_shr_mul<0x111>(p1);
        p2 = dpp_shr_mul<0x111>(p2); p3 = dpp_shr_mul<0x111>(p3);
        p0 = dpp_shr_mul<0x112>(p0); p1 = dpp_shr_mul<0x112>(p1);
        p2 = dpp_shr_mul<0x112>(p2); p3 = dpp_shr_mul<0x112>(p3);
        p0 = dpp_shr_mul<0x114>(p0); p1 = dpp_shr_mul<0x114>(p1);
        p2 = dpp_shr_mul<0x114>(p2); p3 = dpp_shr_mul<0x114>(p3);
        p0 = dpp_shr_mul<0x118>(p0); p1 = dpp_shr_mul<0x118>(p1);
        p2 = dpp_shr_mul<0x118>(p2); p3 = dpp_shr_mul<0x118>(p3);

        float fg  = __fdividef(1.f, 1.f + __expf(-p0));
        float ig  = __fdividef(1.f, 1.f + __expf(-p1));
        float gg2 = 2.f * __fdividef(1.f, 1.f + __expf(-2.f * p2)) - 1.f;
        float og  = __fdividef(1.f, 1.f + __expf(-p3));

        cx = fmaf(fg, cx, ig * gg2);
        float e2 = __expf(cx + cx);
        float th = 1.f - __fdividef(2.f, 1.f + e2);
        hv = og * th;

        if (lane < NW) outp[(size_t)t * (BATCH * NW)] = hv;

        // broadcast hx (lanes 0..9 hold units 0..9) -> uniform SGPRs
#pragma unroll
        for (int j = 0; j < NW; ++j)
            hx_s[j] = __int_as_float(__builtin_amdgcn_readlane(__float_as_int(hv), j));
    }

    if (lane < NW) {
        hxout[b * NW + lane] = hv;
        cxout[b * NW + lane] = cx;
    }
}

extern "C" void kernel_launch(void* const* d_in, const int* in_sizes, int n_in,
                              void* d_out, int out_size, void* d_ws, size_t ws_size,
                              hipStream_t stream) {
    const float* x     = (const float*)d_in[0];  // (64,256,246)
    const float* W     = (const float*)d_in[1];  // (4,10,256)
    const float* bias  = (const float*)d_in[2];  // (4,10)
    const float* theta = (const float*)d_in[3];  // (4,10)

    float* out   = (float*)d_out;                        // (64,256,10)
    float* hxout = out + (size_t)TSTEPS * BATCH * NW;    // (256,10)
    float* cxout = hxout + (size_t)BATCH * NW;           // (256,10)

    float* Wp = (float*)d_ws;                  // 15744 floats

    k_wt<<<(WP_ELEMS + 255) / 256, 256, 0, stream>>>(W, Wp);
    k_fused<<<BATCH, 512, 0, stream>>>(x, Wp, bias, theta, W, out, hxout, cxout);
}